// Round 6
// baseline (407.633 us; speedup 1.0000x reference)
//
#include <hip/hip_runtime.h>
#include <hip/hip_bf16.h>
#include <math.h>

// ---------- types ----------
typedef __bf16 bf16_t;
typedef __bf16 bf16x8 __attribute__((ext_vector_type(8)));
typedef __bf16 bf16x4 __attribute__((ext_vector_type(4)));
typedef float  f32x4  __attribute__((ext_vector_type(4)));

#define B_ 4
#define S_ 4096
#define D_ 1024
#define N_ 256
#define M_ (B_*S_)   // 16384

// fast activations: v_exp_f32 + v_rcp_f32 (~1 ulp each, plenty for bf16 out)
__device__ __forceinline__ float fsig(float x){
    return __builtin_amdgcn_rcpf(1.0f + __expf(-x));
}
__device__ __forceinline__ float ftanh(float x){
    return 1.0f - 2.0f*__builtin_amdgcn_rcpf(1.0f + __expf(2.0f*x));
}

// async global->LDS, 16B per lane (dest = wave-uniform base + lane*16, linear)
__device__ __forceinline__ void gload_lds16(const void* g, void* l){
    __builtin_amdgcn_global_load_lds(
        (const __attribute__((address_space(1))) unsigned int*)g,
        (__attribute__((address_space(3))) unsigned int*)l, 16, 0, 0);
}

// ---------- all weight transposes in one launch ----------
struct TJobs {
    const float* in[7];
    bf16_t*      out[7];
    int R[7];
    int C[7];
};

__global__ void transpose_all(TJobs j){
    int z = blockIdx.z;
    int R = j.R[z], C = j.C[z];
    int c0 = blockIdx.x*32, r0 = blockIdx.y*32;
    if (c0 >= C || r0 >= R) return;
    __shared__ float tile[32][33];
    int tx = threadIdx.x, ty = threadIdx.y;       // x:0..31, y:0..7
    const float* in = j.in[z];
    bf16_t* out = j.out[z];
    #pragma unroll
    for (int i=0;i<32;i+=8)
        tile[ty+i][tx] = in[(size_t)(r0+ty+i)*C + (c0+tx)];
    __syncthreads();
    #pragma unroll
    for (int i=0;i<32;i+=8)
        out[(size_t)(c0+ty+i)*R + (r0+tx)] = (bf16_t)tile[tx][ty+i];
}

// ---------- LayerNorm: x f32 [M][D] -> h bf16 ----------
__global__ void ln_kernel(const float* __restrict__ x, const float* __restrict__ gw,
                          const float* __restrict__ bw, bf16_t* __restrict__ h){
    int row = blockIdx.x;
    int t = threadIdx.x;                           // 256 threads, 4 elems each
    float4 v = ((const float4*)(x + (size_t)row*D_))[t];
    float s = v.x+v.y+v.z+v.w;
    float q = v.x*v.x+v.y*v.y+v.z*v.z+v.w*v.w;
    #pragma unroll
    for (int o=1;o<64;o<<=1){ s += __shfl_xor(s,o,64); q += __shfl_xor(q,o,64); }
    __shared__ float sw[4], sq[4];
    int wid = t>>6;
    if ((t&63)==0){ sw[wid]=s; sq[wid]=q; }
    __syncthreads();
    s = sw[0]+sw[1]+sw[2]+sw[3];
    q = sq[0]+sq[1]+sq[2]+sq[3];
    float mu = s*(1.0f/D_);
    float rs = rsqrtf(q*(1.0f/D_) - mu*mu + 1e-5f);
    float4 gv = ((const float4*)gw)[t];
    float4 bv = ((const float4*)bw)[t];
    bf16x4 o4;
    o4[0] = (bf16_t)((v.x-mu)*rs*gv.x + bv.x);
    o4[1] = (bf16_t)((v.y-mu)*rs*gv.y + bv.y);
    o4[2] = (bf16_t)((v.z-mu)*rs*gv.z + bv.z);
    o4[3] = (bf16_t)((v.w-mu)*rs*gv.w + bv.w);
    *(bf16x4*)(h + (size_t)row*D_ + t*4) = o4;
}

// ---------- depthwise conv1d k=3 pad=1 along S ----------
__global__ void conv_kernel(const bf16_t* __restrict__ h, const float* __restrict__ w,
                            const float* __restrict__ mb, bf16_t* __restrict__ mix){
    int idx = blockIdx.x*256 + threadIdx.x;
    int g8  = idx & 127;
    int row = idx >> 7;                            // b*S + s
    int s   = row & (S_-1);
    int d0  = g8*8;
    const bf16_t* hr = h + (size_t)row*D_ + d0;
    bf16x8 cur = *(const bf16x8*)hr;
    bf16x8 prv, nxt;
    #pragma unroll
    for (int i=0;i<8;i++){ prv[i]=(bf16_t)0.0f; nxt[i]=(bf16_t)0.0f; }
    if (s > 0)      prv = *(const bf16x8*)(hr - D_);
    if (s < S_-1)   nxt = *(const bf16x8*)(hr + D_);
    bf16x8 ov;
    #pragma unroll
    for (int i=0;i<8;i++){
        int d = d0+i;
        float o = (float)prv[i]*w[d*3] + (float)cur[i]*w[d*3+1] + (float)nxt[i]*w[d*3+2] + mb[d];
        ov[i] = (bf16_t)o;
    }
    *(bf16x8*)(mix + (size_t)row*D_ + d0) = ov;
}

// ---------- 128x256 MFMA GEMM: BK=32, 8 waves, 48KB LDS dbuf, 2 blocks/CU ----------
// Flat blockIdx (NO XCD swizzle): dispatch is x-fastest so all XCDs sweep the
// same n0-column together -> A (32MB) stays L3-resident across columns.
// (Round-5 XCD swizzle gave each XCD a different column: FETCH 72->189MB. Reverted.)
struct Epi {
    const float *b0,*b1,*b2,*b3,*b4;
    bf16_t *u, *g, *z;
    bf16_t *xs, *dc, *sel;
    const bf16_t *gbuf, *ubuf;
    const float *resid;
    float *outp;
};

#define WAITV3()  asm volatile("s_waitcnt vmcnt(3)" ::: "memory")
#define WAITV0()  asm volatile("s_waitcnt vmcnt(0)" ::: "memory")
#define WAITLGK0() asm volatile("s_waitcnt lgkmcnt(0)" ::: "memory")
#define CFENCE()  asm volatile("" ::: "memory")
#define BARR()    __builtin_amdgcn_s_barrier()

template<int MODE>
__global__ __launch_bounds__(512,4)
void gemm128(const bf16_t* __restrict__ A, const bf16_t* __restrict__ Bt,
             int K, Epi e){
    extern __shared__ __align__(16) char lds[];
    const int ATILE = 8192;                 // 128x32 bf16
    const int BTILE = 16384;                // 256x32 bf16
    int t = threadIdx.x;
    int wave = t>>6, lane = t&63;
    int wm = (wave>>2)*64;                  // 2 wave-rows x 64
    int wn = (wave&3)*64;                   // 4 wave-cols x 64
    int lm = lane&15, quad = lane>>4;

    int m0 = blockIdx.x*128;
    int n0 = blockIdx.y*256;
    int NT = K>>5;

    const bf16_t* gA = A  + (size_t)(m0 + (t>>2))*K + (t&3)*8;
    const bf16_t* gB = Bt + (size_t)(n0 + (t>>2))*K + (t&3)*8;

    auto stage = [&](int kt, int buf){
        const bf16_t* a = gA + kt*32;
        const bf16_t* b = gB + kt*32;
        char* da = lds + buf*ATILE + t*16;
        char* db = lds + 16384 + buf*BTILE + t*16;
        gload_lds16(a, da);                       // A rows 0..127
        gload_lds16(b, db);                       // B rows 0..127
        gload_lds16(b + (size_t)128*K, db + 8192);// B rows 128..255
    };

    int raBase = (wm+lm)*64 + quad*16;
    int rbBase = (wn+lm)*64 + quad*16;

    f32x4 acc[4][4];
    #pragma unroll
    for (int i=0;i<4;i++)
        #pragma unroll
        for (int j=0;j<4;j++)
            #pragma unroll
            for (int r=0;r<4;r++) acc[i][j][r]=0.0f;

    bf16x8 aF[4], bF[4];

    stage(0,0);
    stage(1,1);
    WAITV3();                    // tile 0 landed; tile 1's 3 loads in flight
    BARR();
    CFENCE();

    for (int kt=0; kt<NT; ++kt){
        int buf = kt&1;
        const char* pa = lds + buf*ATILE + raBase;
        const char* pb = lds + 16384 + buf*BTILE + rbBase;

        #pragma unroll
        for (int j=0;j<4;j++) bF[j] = *(const bf16x8*)(pb + j*1024);
        #pragma unroll
        for (int i=0;i<4;i++) aF[i] = *(const bf16x8*)(pa + i*1024);

        #pragma unroll
        for (int i=0;i<4;i++)
            #pragma unroll
            for (int j=0;j<4;j++)
                acc[i][j] = __builtin_amdgcn_mfma_f32_16x16x32_bf16(aF[i], bF[j], acc[i][j], 0,0,0);

        WAITLGK0();                      // all LDS reads of buf retired
        BARR();
        CFENCE();
        if (kt+2 < NT){
            stage(kt+2, buf);            // refill just-retired buffer
            WAITV3();                    // tile kt+1 landed; kt+2's 3 in flight
            BARR();
            CFENCE();
        } else if (kt+1 < NT){
            WAITV0();                    // tail drain
            BARR();
            CFENCE();
        }
    }
    __syncthreads();

    // ---- epilogue: retile through LDS for coalesced global I/O ----
    // acc layout: row = wm + i*16 + quad*4 + r, col = wn + j*16 + lm (128x256 tile)
    // Tb stride 260 bf16 (130 dw): quad step = 520B = 8 banks -> 64 write lanes
    // partition all 32 banks exactly 2/bank (bf16 pair) -> conflict-free.
    if (MODE==0 || MODE==1){
        const float* bp = e.b0; int cbase = 0; bf16_t* dst = 0; int width = D_;
        bool ut = true;
        if (MODE==0){
            ut = (n0 < 1280);
            if (n0 < 1024){ bp=e.b0; cbase=n0; dst=e.u; width=D_; }
            else if (n0 < 1792){
                int sub=(n0-1024)>>8;
                bp  = sub==0? e.b1 : sub==1? e.b2 : e.b3;
                dst = sub==0? e.xs : sub==1? e.dc : e.sel;
                cbase = 0; width = N_;
            } else { bp=e.b4; cbase=n0-1792; dst=e.g; width=D_; }
        } else {
            bp = e.b0; cbase = n0; width = D_;
        }
        bf16_t* Tb = (bf16_t*)lds;
        #pragma unroll
        for (int h=0; h<2; h++){                      // 64-row bands, stride 260
            if (h) __syncthreads();
            if (wm == h*64){
                #pragma unroll
                for (int ii=0;ii<4;ii++){
                    #pragma unroll
                    for (int j=0;j<4;j++){
                        float bv = bp[(MODE==0?cbase:n0) + wn + j*16 + lm];
                        #pragma unroll
                        for (int r=0;r<4;r++){
                            float v = acc[ii][j][r] + bv;
                            if (MODE==0) v = ut ? ftanh(v) : fsig(v);
                            Tb[(ii*16+quad*4+r)*260 + wn + j*16 + lm] = (bf16_t)v;
                        }
                    }
                }
            }
            __syncthreads();
            if (MODE==0){
                #pragma unroll
                for (int it=0; it<4; it++){
                    int idx = it*512 + t;
                    int row = idx>>5, c8 = idx&31;
                    bf16x8 v = *(const bf16x8*)&Tb[row*260 + c8*8];
                    *(bf16x8*)&dst[(size_t)(m0 + h*64 + row)*width + cbase + c8*8] = v;
                }
            } else {
                #pragma unroll
                for (int it=0; it<4; it++){
                    int idx = it*512 + t;
                    int row = idx>>5, c8 = idx&31;
                    bf16x8 y = *(const bf16x8*)&Tb[row*260 + c8*8];
                    size_t gi = (size_t)(m0 + h*64 + row)*D_ + n0 + c8*8;
                    bf16x8 gv = *(const bf16x8*)&e.gbuf[gi];
                    bf16x8 uv = *(const bf16x8*)&e.ubuf[gi];
                    bf16x8 o;
                    #pragma unroll
                    for (int q=0;q<8;q++){
                        float gf = (float)gv[q];
                        o[q] = (bf16_t)(gf*(float)y[q] + (1.0f-gf)*(float)uv[q]);
                    }
                    *(bf16x8*)&e.z[gi] = o;
                }
            }
        }
    } else {
        float* T = (float*)lds;
        #pragma unroll
        for (int pZ=0; pZ<4; pZ++){                   // 32-row bands, stride 260
            if (pZ) __syncthreads();
            if (wm == (pZ>>1)*64){
                int ib = (pZ&1)*2;
                #pragma unroll
                for (int ii=0;ii<2;ii++){
                    #pragma unroll
                    for (int j=0;j<4;j++)
                        #pragma unroll
                        for (int r=0;r<4;r++)
                            T[(ii*16+quad*4+r)*260 + wn + j*16 + lm] = acc[ib+ii][j][r];
                }
            }
            __syncthreads();
            #pragma unroll
            for (int it=0; it<4; it++){
                int idx = it*512 + t;
                int row = idx>>6, c4 = idx&63;
                f32x4 v = *(const f32x4*)&T[row*260 + c4*4];
                size_t gi = (size_t)(m0 + pZ*32 + row)*D_ + n0 + c4*4;
                float4 res = *(const float4*)&e.resid[gi];
                float4 bb  = *(const float4*)&e.b0[n0 + c4*4];
                float4 o;
                o.x = v[0]+res.x+bb.x; o.y = v[1]+res.y+bb.y;
                o.z = v[2]+res.z+bb.z; o.w = v[3]+res.w+bb.w;
                *(float4*)&e.outp[gi] = o;
            }
        }
    }
}

// ---------- chunked affine scan: state = d*state + (1-d)*x (bf16 in, bf16 out) ----------
// one wave per (b,chunk); each lane owns 4 contiguous channels (bf16x4 = 8B/lane)
__global__ void scan_p1(const bf16_t* __restrict__ dc, const bf16_t* __restrict__ xs,
                        float* __restrict__ aggA, float* __restrict__ aggB){
    int wg4 = blockIdx.x*4 + (threadIdx.x>>6);     // b*64 + chunk
    int b = wg4>>6, ch = wg4&63;
    int l4 = (threadIdx.x&63)*4;
    size_t base = ((size_t)b*S_ + ch*64)*N_ + l4;
    float A0=1.f,A1=1.f,A2=1.f,A3=1.f, B0=0.f,B1=0.f,B2=0.f,B3=0.f;
    for (int t=0;t<64;t++){
        bf16x4 d4 = *(const bf16x4*)(dc + base + (size_t)t*N_);
        bf16x4 x4 = *(const bf16x4*)(xs + base + (size_t)t*N_);
        float d;
        d=(float)d4[0]; A0*=d; B0=d*B0+(1.f-d)*(float)x4[0];
        d=(float)d4[1]; A1*=d; B1=d*B1+(1.f-d)*(float)x4[1];
        d=(float)d4[2]; A2*=d; B2=d*B2+(1.f-d)*(float)x4[2];
        d=(float)d4[3]; A3*=d; B3=d*B3+(1.f-d)*(float)x4[3];
    }
    size_t o = (size_t)wg4*N_ + l4;
    float4 av; av.x=A0; av.y=A1; av.z=A2; av.w=A3;
    float4 bv; bv.x=B0; bv.y=B1; bv.z=B2; bv.w=B3;
    *(float4*)(aggA+o) = av;
    *(float4*)(aggB+o) = bv;
}

__global__ void scan_p2(const float* __restrict__ aggA, const float* __restrict__ aggB,
                        float* __restrict__ pre){
    int b = blockIdx.x, n = threadIdx.x;
    float s = 0.0f;
    for (int ch=0; ch<64; ch++){
        size_t i = ((size_t)b*64+ch)*N_+n;
        pre[i] = s;
        s = aggA[i]*s + aggB[i];
    }
}

__global__ void scan_p3(const bf16_t* __restrict__ dc, const bf16_t* __restrict__ xs,
                        const bf16_t* __restrict__ sel, const float* __restrict__ pre,
                        bf16_t* __restrict__ ss){
    int wg4 = blockIdx.x*4 + (threadIdx.x>>6);
    int b = wg4>>6, ch = wg4&63;
    int l4 = (threadIdx.x&63)*4;
    size_t base = ((size_t)b*S_ + ch*64)*N_ + l4;
    size_t o = (size_t)wg4*N_ + l4;
    float4 pv = *(const float4*)(pre+o);
    float s0=pv.x, s1=pv.y, s2=pv.z, s3=pv.w;
    for (int t=0;t<64;t++){
        size_t i = base + (size_t)t*N_;
        bf16x4 d4 = *(const bf16x4*)(dc+i);
        bf16x4 x4 = *(const bf16x4*)(xs+i);
        bf16x4 e4 = *(const bf16x4*)(sel+i);
        float d;
        d=(float)d4[0]; s0=d*s0+(1.f-d)*(float)x4[0];
        d=(float)d4[1]; s1=d*s1+(1.f-d)*(float)x4[1];
        d=(float)d4[2]; s2=d*s2+(1.f-d)*(float)x4[2];
        d=(float)d4[3]; s3=d*s3+(1.f-d)*(float)x4[3];
        bf16x4 o4;
        o4[0]=(bf16_t)((float)e4[0]*s0);
        o4[1]=(bf16_t)((float)e4[1]*s1);
        o4[2]=(bf16_t)((float)e4[2]*s2);
        o4[3]=(bf16_t)((float)e4[3]*s3);
        *(bf16x4*)(ss+i) = o4;
    }
}

// ---------- launch ----------
extern "C" void kernel_launch(void* const* d_in, const int* in_sizes, int n_in,
                              void* d_out, int out_size, void* d_ws, size_t ws_size,
                              hipStream_t stream){
    const float* x    = (const float*)d_in[0];
    const float* ln_g = (const float*)d_in[1];
    const float* ln_b = (const float*)d_in[2];
    const float* mixw = (const float*)d_in[3];
    const float* mixb = (const float*)d_in[4];
    const float* Wi   = (const float*)d_in[5];
    const float* bi   = (const float*)d_in[6];
    const float* Wsin = (const float*)d_in[7];
    const float* bsin = (const float*)d_in[8];
    const float* Wd   = (const float*)d_in[9];
    const float* bd   = (const float*)d_in[10];
    const float* Wsel = (const float*)d_in[11];
    const float* bsel = (const float*)d_in[12];
    const float* Wso  = (const float*)d_in[13];
    const float* bso  = (const float*)d_in[14];
    const float* Wg   = (const float*)d_in[15];
    const float* bg   = (const float*)d_in[16];
    const float* Wout = (const float*)d_in[17];
    const float* bout = (const float*)d_in[18];
    float* out = (float*)d_out;

    char* p = (char*)d_ws;
    auto alloc = [&](size_t bytes)->char*{ char* r=p; p += (bytes+255)&~(size_t)255; return r; };
    bf16_t* hB    = (bf16_t*)alloc((size_t)M_*D_*2);
    bf16_t* mixB  = (bf16_t*)alloc((size_t)M_*D_*2);
    bf16_t* uB    = (bf16_t*)alloc((size_t)M_*D_*2);
    bf16_t* gB    = (bf16_t*)alloc((size_t)M_*D_*2);
    bf16_t* ssB   = (bf16_t*)alloc((size_t)M_*N_*2);
    bf16_t* xs    = (bf16_t*)alloc((size_t)M_*N_*2);
    bf16_t* dc    = (bf16_t*)alloc((size_t)M_*N_*2);
    bf16_t* sel   = (bf16_t*)alloc((size_t)M_*N_*2);
    bf16_t* WbigT = (bf16_t*)alloc((size_t)2816*1024*2);
    bf16_t* WsoT  = (bf16_t*)alloc(1024*256*2);
    bf16_t* WoutT = (bf16_t*)alloc(1024*1024*2);
    float*  aggA  = (float*)alloc((size_t)4*64*256*4);
    float*  aggB  = (float*)alloc((size_t)4*64*256*4);
    float*  pre   = (float*)alloc((size_t)4*64*256*4);
    bf16_t* zB = mixB;

    TJobs tj;
    tj.in[0]=Wi;   tj.out[0]=WbigT;            tj.R[0]=1024; tj.C[0]=1024;
    tj.in[1]=Wsin; tj.out[1]=WbigT+1024*1024;  tj.R[1]=1024; tj.C[1]=256;
    tj.in[2]=Wd;   tj.out[2]=WbigT+1280*1024;  tj.R[2]=1024; tj.C[2]=256;
    tj.in[3]=Wsel; tj.out[3]=WbigT+1536*1024;  tj.R[3]=1024; tj.C[3]=256;
    tj.in[4]=Wg;   tj.out[4]=WbigT+(size_t)1792*1024; tj.R[4]=1024; tj.C[4]=1024;
    tj.in[5]=Wso;  tj.out[5]=WsoT;             tj.R[5]=256;  tj.C[5]=1024;
    tj.in[6]=Wout; tj.out[6]=WoutT;            tj.R[6]=1024; tj.C[6]=1024;
    transpose_all<<<dim3(32,32,7), dim3(32,8), 0, stream>>>(tj);

    ln_kernel  <<<M_, 256, 0, stream>>>(x, ln_g, ln_b, hB);
    conv_kernel<<<M_*128/256, 256, 0, stream>>>(hB, mixw, mixb, mixB);

    Epi e0 = {};
    e0.b0=bi; e0.b1=bsin; e0.b2=bd; e0.b3=bsel; e0.b4=bg;
    e0.u=uB; e0.g=gB; e0.xs=xs; e0.dc=dc; e0.sel=sel;
    gemm128<0><<<dim3(M_/128, 11), 512, 49152, stream>>>(mixB, WbigT, 1024, e0);

    scan_p1<<<64, 256, 0, stream>>>(dc, xs, aggA, aggB);
    scan_p2<<<4,  256, 0, stream>>>(aggA, aggB, pre);
    scan_p3<<<64, 256, 0, stream>>>(dc, xs, sel, pre, ssB);

    Epi e1 = {};
    e1.b0=bso; e1.gbuf=gB; e1.ubuf=uB; e1.z=zB;
    gemm128<1><<<dim3(M_/128, 4), 512, 49152, stream>>>(ssB, WsoT, 256, e1);

    Epi e2 = {};
    e2.b0=bout; e2.resid=x; e2.outp=out;
    gemm128<2><<<dim3(M_/128, 4), 512, 49152, stream>>>(zB, WoutT, 1024, e2);
}

// Round 9
// 402.330 us; speedup vs baseline: 1.0132x; 1.0132x over previous
//
#include <hip/hip_runtime.h>
#include <hip/hip_bf16.h>
#include <math.h>

// ---------- types ----------
typedef __bf16 bf16_t;
typedef __bf16 bf16x8 __attribute__((ext_vector_type(8)));
typedef __bf16 bf16x4 __attribute__((ext_vector_type(4)));
typedef float  f32x4  __attribute__((ext_vector_type(4)));

#define B_ 4
#define S_ 4096
#define D_ 1024
#define N_ 256
#define M_ (B_*S_)   // 16384

// fast activations: v_exp_f32 + v_rcp_f32 (~1 ulp each, plenty for bf16 out)
__device__ __forceinline__ float fsig(float x){
    return __builtin_amdgcn_rcpf(1.0f + __expf(-x));
}
__device__ __forceinline__ float ftanh(float x){
    return 1.0f - 2.0f*__builtin_amdgcn_rcpf(1.0f + __expf(2.0f*x));
}

// async global->LDS, 16B per lane (dest = wave-uniform base + lane*16, linear)
__device__ __forceinline__ void gload_lds16(const void* g, void* l){
    __builtin_amdgcn_global_load_lds(
        (const __attribute__((address_space(1))) unsigned int*)g,
        (__attribute__((address_space(3))) unsigned int*)l, 16, 0, 0);
}

// ---------- all weight transposes in one launch ----------
struct TJobs {
    const float* in[7];
    bf16_t*      out[7];
    int R[7];
    int C[7];
};

__global__ void transpose_all(TJobs j){
    int z = blockIdx.z;
    int R = j.R[z], C = j.C[z];
    int c0 = blockIdx.x*32, r0 = blockIdx.y*32;
    if (c0 >= C || r0 >= R) return;
    __shared__ float tile[32][33];
    int tx = threadIdx.x, ty = threadIdx.y;       // x:0..31, y:0..7
    const float* in = j.in[z];
    bf16_t* out = j.out[z];
    #pragma unroll
    for (int i=0;i<32;i+=8)
        tile[ty+i][tx] = in[(size_t)(r0+ty+i)*C + (c0+tx)];
    __syncthreads();
    #pragma unroll
    for (int i=0;i<32;i+=8)
        out[(size_t)(c0+ty+i)*R + (r0+tx)] = (bf16_t)tile[tx][ty+i];
}

// ---------- LayerNorm: x f32 [M][D] -> h bf16 ----------
__global__ void ln_kernel(const float* __restrict__ x, const float* __restrict__ gw,
                          const float* __restrict__ bw, bf16_t* __restrict__ h){
    int row = blockIdx.x;
    int t = threadIdx.x;                           // 256 threads, 4 elems each
    float4 v = ((const float4*)(x + (size_t)row*D_))[t];
    float s = v.x+v.y+v.z+v.w;
    float q = v.x*v.x+v.y*v.y+v.z*v.z+v.w*v.w;
    #pragma unroll
    for (int o=1;o<64;o<<=1){ s += __shfl_xor(s,o,64); q += __shfl_xor(q,o,64); }
    __shared__ float sw[4], sq[4];
    int wid = t>>6;
    if ((t&63)==0){ sw[wid]=s; sq[wid]=q; }
    __syncthreads();
    s = sw[0]+sw[1]+sw[2]+sw[3];
    q = sq[0]+sq[1]+sq[2]+sq[3];
    float mu = s*(1.0f/D_);
    float rs = rsqrtf(q*(1.0f/D_) - mu*mu + 1e-5f);
    float4 gv = ((const float4*)gw)[t];
    float4 bv = ((const float4*)bw)[t];
    bf16x4 o4;
    o4[0] = (bf16_t)((v.x-mu)*rs*gv.x + bv.x);
    o4[1] = (bf16_t)((v.y-mu)*rs*gv.y + bv.y);
    o4[2] = (bf16_t)((v.z-mu)*rs*gv.z + bv.z);
    o4[3] = (bf16_t)((v.w-mu)*rs*gv.w + bv.w);
    *(bf16x4*)(h + (size_t)row*D_ + t*4) = o4;
}

// ---------- depthwise conv1d k=3 pad=1 along S ----------
__global__ void conv_kernel(const bf16_t* __restrict__ h, const float* __restrict__ w,
                            const float* __restrict__ mb, bf16_t* __restrict__ mix){
    int idx = blockIdx.x*256 + threadIdx.x;
    int g8  = idx & 127;
    int row = idx >> 7;                            // b*S + s
    int s   = row & (S_-1);
    int d0  = g8*8;
    const bf16_t* hr = h + (size_t)row*D_ + d0;
    bf16x8 cur = *(const bf16x8*)hr;
    bf16x8 prv, nxt;
    #pragma unroll
    for (int i=0;i<8;i++){ prv[i]=(bf16_t)0.0f; nxt[i]=(bf16_t)0.0f; }
    if (s > 0)      prv = *(const bf16x8*)(hr - D_);
    if (s < S_-1)   nxt = *(const bf16x8*)(hr + D_);
    bf16x8 ov;
    #pragma unroll
    for (int i=0;i<8;i++){
        int d = d0+i;
        float o = (float)prv[i]*w[d*3] + (float)cur[i]*w[d*3+1] + (float)nxt[i]*w[d*3+2] + mb[d];
        ov[i] = (bf16_t)o;
    }
    *(bf16x8*)(mix + (size_t)row*D_ + d0) = ov;
}

// ---------- 128x256 MFMA GEMM: BK=32, 8 waves, TRIPLE-buffered 72KB LDS ----------
// 3-buffer pipeline (race-free version of the r8 zero-register pipeline):
// tile kt+1 is certified landed by ALL waves one iteration early (each wave's
// vmcnt(3) at iter kt-1 + the barrier at top of iter kt), so fragment reloads
// for tile kt+1 can overlap iter kt's MFMAs. One barrier per tile.
//   iter kt: lgkmcnt(0); barrier;            // buf[kt%3] free; kt+1 certified
//            stage(kt+3, buf[kt%3]); vmcnt(3)  (tail: vmcnt(0))
//            16 MFMA interleaved with WAR-pinned reloads from buf[(kt+1)%3]
struct Epi {
    const float *b0,*b1,*b2,*b3,*b4;
    bf16_t *u, *g, *z;
    bf16_t *xs, *dc, *sel;
    const bf16_t *gbuf, *ubuf;
    const float *resid;
    float *outp;
};

#define WAITV3()  asm volatile("s_waitcnt vmcnt(3)" ::: "memory")
#define WAITV0()  asm volatile("s_waitcnt vmcnt(0)" ::: "memory")
#define WAITLGK0() asm volatile("s_waitcnt lgkmcnt(0)" ::: "memory")
#define CFENCE()  asm volatile("" ::: "memory")
#define BARR()    __builtin_amdgcn_s_barrier()

template<int MODE>
__global__ __launch_bounds__(512,4)
void gemm128(const bf16_t* __restrict__ A, const bf16_t* __restrict__ Bt,
             int K, Epi e){
    __shared__ __align__(16) char lds[73728];   // A 3x8KB @0, B 3x16KB @24576
    int t = threadIdx.x;
    int wave = t>>6, lane = t&63;
    int wm = (wave>>2)*64;                  // 2 wave-rows x 64
    int wn = (wave&3)*64;                   // 4 wave-cols x 64
    int lm = lane&15, quad = lane>>4;

    int m0 = blockIdx.x*128;
    int n0 = blockIdx.y*256;
    int NT = K>>5;                          // 32 or 8 (>=3)

    const bf16_t* gA = A  + (size_t)(m0 + (t>>2))*K + (t&3)*8;
    const bf16_t* gB = Bt + (size_t)(n0 + (t>>2))*K + (t&3)*8;

    auto stage = [&](int kt){
        int x = kt % 3;
        const bf16_t* a = gA + kt*32;
        const bf16_t* b = gB + kt*32;
        char* da = lds + x*8192  + t*16;
        char* db = lds + 24576 + x*16384 + t*16;
        gload_lds16(a, da);                       // A rows 0..127
        gload_lds16(b, db);                       // B rows 0..127
        gload_lds16(b + (size_t)128*K, db + 8192);// B rows 128..255
    };

    int raBase = (wm+lm)*64 + quad*16;
    int rbBase = (wn+lm)*64 + quad*16;

    f32x4 acc[4][4];
    #pragma unroll
    for (int i=0;i<4;i++)
        #pragma unroll
        for (int j=0;j<4;j++)
            #pragma unroll
            for (int r=0;r<4;r++) acc[i][j][r]=0.0f;

    bf16x8 aF[4], bF[4];

    // ---- prologue: stage tiles 0,1,2; certify 0,1; load frags(0) ----
    stage(0);
    stage(1);
    stage(2);
    WAITV3();                    // 6 oldest done: tiles 0,1 certified (own)
    BARR();                      // ...certified by ALL waves
    CFENCE();
    {
        const char* pa = lds + raBase;              // buf0
        const char* pb = lds + 24576 + rbBase;
        #pragma unroll
        for (int j=0;j<4;j++) bF[j] = *(const bf16x8*)(pb + j*1024);
        #pragma unroll
        for (int i=0;i<4;i++) aF[i] = *(const bf16x8*)(pa + i*1024);
    }

    for (int kt=0; kt<NT; ++kt){
        WAITLGK0();                      // our frag reads of tile kt complete
        BARR();                          // buf[kt%3] free; tiles<=kt+1 certified
        CFENCE();
        if (kt+3 < NT){
            stage(kt+3);                 // into buf[kt%3]; overlaps MFMAs
            WAITV3();                    // certify tile kt+2; kt+3's 3 in flight
        } else {
            WAITV0();                    // tail: certify everything outstanding
        }
        CFENCE();

        bool more = (kt+1 < NT);
        int xn = (kt+1) % 3;
        const char* pan = lds + xn*8192  + raBase;
        const char* pbn = lds + 24576 + xn*16384 + rbBase;

        // j-outer MFMAs; reload bF[j] from tile kt+1 right after its last use
        #pragma unroll
        for (int j=0;j<4;j++){
            #pragma unroll
            for (int i=0;i<4;i++)
                acc[i][j] = __builtin_amdgcn_mfma_f32_16x16x32_bf16(aF[i], bF[j], acc[i][j], 0,0,0);
            if (more) bF[j] = *(const bf16x8*)(pbn + j*1024);
        }
        if (more){
            #pragma unroll
            for (int i=0;i<4;i++) aF[i] = *(const bf16x8*)(pan + i*1024);
        }
    }
    __syncthreads();

    // ---- epilogue: retile through LDS for coalesced global I/O ----
    // acc layout: row = wm + i*16 + quad*4 + r, col = wn + j*16 + lm (128x256 tile)
    if (MODE==0 || MODE==1){
        const float* bp = e.b0; int cbase = 0; bf16_t* dst = 0; int width = D_;
        bool ut = true;
        if (MODE==0){
            ut = (n0 < 1280);
            if (n0 < 1024){ bp=e.b0; cbase=n0; dst=e.u; width=D_; }
            else if (n0 < 1792){
                int sub=(n0-1024)>>8;
                bp  = sub==0? e.b1 : sub==1? e.b2 : e.b3;
                dst = sub==0? e.xs : sub==1? e.dc : e.sel;
                cbase = 0; width = N_;
            } else { bp=e.b4; cbase=n0-1792; dst=e.g; width=D_; }
        } else {
            bp = e.b0; cbase = n0; width = D_;
        }
        bf16_t* Tb = (bf16_t*)lds;
        #pragma unroll
        for (int h=0; h<2; h++){                      // 64-row bands, stride 260
            if (h) __syncthreads();
            if (wm == h*64){
                #pragma unroll
                for (int ii=0;ii<4;ii++){
                    #pragma unroll
                    for (int j=0;j<4;j++){
                        float bv = bp[(MODE==0?cbase:n0) + wn + j*16 + lm];
                        #pragma unroll
                        for (int r=0;r<4;r++){
                            float v = acc[ii][j][r] + bv;
                            if (MODE==0) v = ut ? ftanh(v) : fsig(v);
                            Tb[(ii*16+quad*4+r)*260 + wn + j*16 + lm] = (bf16_t)v;
                        }
                    }
                }
            }
            __syncthreads();
            if (MODE==0){
                #pragma unroll
                for (int it=0; it<4; it++){
                    int idx = it*512 + t;
                    int row = idx>>5, c8 = idx&31;
                    bf16x8 v = *(const bf16x8*)&Tb[row*260 + c8*8];
                    *(bf16x8*)&dst[(size_t)(m0 + h*64 + row)*width + cbase + c8*8] = v;
                }
            } else {
                #pragma unroll
                for (int it=0; it<4; it++){
                    int idx = it*512 + t;
                    int row = idx>>5, c8 = idx&31;
                    bf16x8 y = *(const bf16x8*)&Tb[row*260 + c8*8];
                    size_t gi = (size_t)(m0 + h*64 + row)*D_ + n0 + c8*8;
                    bf16x8 gv = *(const bf16x8*)&e.gbuf[gi];
                    bf16x8 uv = *(const bf16x8*)&e.ubuf[gi];
                    bf16x8 o;
                    #pragma unroll
                    for (int q=0;q<8;q++){
                        float gf = (float)gv[q];
                        o[q] = (bf16_t)(gf*(float)y[q] + (1.0f-gf)*(float)uv[q]);
                    }
                    *(bf16x8*)&e.z[gi] = o;
                }
            }
        }
    } else {
        float* T = (float*)lds;
        #pragma unroll
        for (int pZ=0; pZ<4; pZ++){                   // 32-row bands, stride 260
            if (pZ) __syncthreads();
            if (wm == (pZ>>1)*64){
                int ib = (pZ&1)*2;
                #pragma unroll
                for (int ii=0;ii<2;ii++){
                    #pragma unroll
                    for (int j=0;j<4;j++)
                        #pragma unroll
                        for (int r=0;r<4;r++)
                            T[(ii*16+quad*4+r)*260 + wn + j*16 + lm] = acc[ib+ii][j][r];
                }
            }
            __syncthreads();
            #pragma unroll
            for (int it=0; it<4; it++){
                int idx = it*512 + t;
                int row = idx>>6, c4 = idx&63;
                f32x4 v = *(const f32x4*)&T[row*260 + c4*4];
                size_t gi = (size_t)(m0 + pZ*32 + row)*D_ + n0 + c4*4;
                float4 res = *(const float4*)&e.resid[gi];
                float4 bb  = *(const float4*)&e.b0[n0 + c4*4];
                float4 o;
                o.x = v[0]+res.x+bb.x; o.y = v[1]+res.y+bb.y;
                o.z = v[2]+res.z+bb.z; o.w = v[3]+res.w+bb.w;
                *(float4*)&e.outp[gi] = o;
            }
        }
    }
}

// ---------- chunked affine scan: state = d*state + (1-d)*x (bf16 in, bf16 out) ----------
// one wave per (b,chunk); each lane owns 4 contiguous channels (bf16x4 = 8B/lane)
__global__ void scan_p1(const bf16_t* __restrict__ dc, const bf16_t* __restrict__ xs,
                        float* __restrict__ aggA, float* __restrict__ aggB){
    int wg4 = blockIdx.x*4 + (threadIdx.x>>6);     // b*64 + chunk
    int b = wg4>>6, ch = wg4&63;
    int l4 = (threadIdx.x&63)*4;
    size_t base = ((size_t)b*S_ + ch*64)*N_ + l4;
    float A0=1.f,A1=1.f,A2=1.f,A3=1.f, B0=0.f,B1=0.f,B2=0.f,B3=0.f;
    for (int t=0;t<64;t++){
        bf16x4 d4 = *(const bf16x4*)(dc + base + (size_t)t*N_);
        bf16x4 x4 = *(const bf16x4*)(xs + base + (size_t)t*N_);
        float d;
        d=(float)d4[0]; A0*=d; B0=d*B0+(1.f-d)*(float)x4[0];
        d=(float)d4[1]; A1*=d; B1=d*B1+(1.f-d)*(float)x4[1];
        d=(float)d4[2]; A2*=d; B2=d*B2+(1.f-d)*(float)x4[2];
        d=(float)d4[3]; A3*=d; B3=d*B3+(1.f-d)*(float)x4[3];
    }
    size_t o = (size_t)wg4*N_ + l4;
    float4 av; av.x=A0; av.y=A1; av.z=A2; av.w=A3;
    float4 bv; bv.x=B0; bv.y=B1; bv.z=B2; bv.w=B3;
    *(float4*)(aggA+o) = av;
    *(float4*)(aggB+o) = bv;
}

__global__ void scan_p2(const float* __restrict__ aggA, const float* __restrict__ aggB,
                        float* __restrict__ pre){
    int b = blockIdx.x, n = threadIdx.x;
    float s = 0.0f;
    for (int ch=0; ch<64; ch++){
        size_t i = ((size_t)b*64+ch)*N_+n;
        pre[i] = s;
        s = aggA[i]*s + aggB[i];
    }
}

__global__ void scan_p3(const bf16_t* __restrict__ dc, const bf16_t* __restrict__ xs,
                        const bf16_t* __restrict__ sel, const float* __restrict__ pre,
                        bf16_t* __restrict__ ss){
    int wg4 = blockIdx.x*4 + (threadIdx.x>>6);
    int b = wg4>>6, ch = wg4&63;
    int l4 = (threadIdx.x&63)*4;
    size_t base = ((size_t)b*S_ + ch*64)*N_ + l4;
    size_t o = (size_t)wg4*N_ + l4;
    float4 pv = *(const float4*)(pre+o);
    float s0=pv.x, s1=pv.y, s2=pv.z, s3=pv.w;
    for (int t=0;t<64;t++){
        size_t i = base + (size_t)t*N_;
        bf16x4 d4 = *(const bf16x4*)(dc+i);
        bf16x4 x4 = *(const bf16x4*)(xs+i);
        bf16x4 e4 = *(const bf16x4*)(sel+i);
        float d;
        d=(float)d4[0]; s0=d*s0+(1.f-d)*(float)x4[0];
        d=(float)d4[1]; s1=d*s1+(1.f-d)*(float)x4[1];
        d=(float)d4[2]; s2=d*s2+(1.f-d)*(float)x4[2];
        d=(float)d4[3]; s3=d*s3+(1.f-d)*(float)x4[3];
        bf16x4 o4;
        o4[0]=(bf16_t)((float)e4[0]*s0);
        o4[1]=(bf16_t)((float)e4[1]*s1);
        o4[2]=(bf16_t)((float)e4[2]*s2);
        o4[3]=(bf16_t)((float)e4[3]*s3);
        *(bf16x4*)(ss+i) = o4;
    }
}

// ---------- launch ----------
extern "C" void kernel_launch(void* const* d_in, const int* in_sizes, int n_in,
                              void* d_out, int out_size, void* d_ws, size_t ws_size,
                              hipStream_t stream){
    const float* x    = (const float*)d_in[0];
    const float* ln_g = (const float*)d_in[1];
    const float* ln_b = (const float*)d_in[2];
    const float* mixw = (const float*)d_in[3];
    const float* mixb = (const float*)d_in[4];
    const float* Wi   = (const float*)d_in[5];
    const float* bi   = (const float*)d_in[6];
    const float* Wsin = (const float*)d_in[7];
    const float* bsin = (const float*)d_in[8];
    const float* Wd   = (const float*)d_in[9];
    const float* bd   = (const float*)d_in[10];
    const float* Wsel = (const float*)d_in[11];
    const float* bsel = (const float*)d_in[12];
    const float* Wso  = (const float*)d_in[13];
    const float* bso  = (const float*)d_in[14];
    const float* Wg   = (const float*)d_in[15];
    const float* bg   = (const float*)d_in[16];
    const float* Wout = (const float*)d_in[17];
    const float* bout = (const float*)d_in[18];
    float* out = (float*)d_out;

    char* p = (char*)d_ws;
    auto alloc = [&](size_t bytes)->char*{ char* r=p; p += (bytes+255)&~(size_t)255; return r; };
    bf16_t* hB    = (bf16_t*)alloc((size_t)M_*D_*2);
    bf16_t* mixB  = (bf16_t*)alloc((size_t)M_*D_*2);
    bf16_t* uB    = (bf16_t*)alloc((size_t)M_*D_*2);
    bf16_t* gB    = (bf16_t*)alloc((size_t)M_*D_*2);
    bf16_t* ssB   = (bf16_t*)alloc((size_t)M_*N_*2);
    bf16_t* xs    = (bf16_t*)alloc((size_t)M_*N_*2);
    bf16_t* dc    = (bf16_t*)alloc((size_t)M_*N_*2);
    bf16_t* sel   = (bf16_t*)alloc((size_t)M_*N_*2);
    bf16_t* WbigT = (bf16_t*)alloc((size_t)2816*1024*2);
    bf16_t* WsoT  = (bf16_t*)alloc(1024*256*2);
    bf16_t* WoutT = (bf16_t*)alloc(1024*1024*2);
    float*  aggA  = (float*)alloc((size_t)4*64*256*4);
    float*  aggB  = (float*)alloc((size_t)4*64*256*4);
    float*  pre   = (float*)alloc((size_t)4*64*256*4);
    bf16_t* zB = mixB;

    TJobs tj;
    tj.in[0]=Wi;   tj.out[0]=WbigT;            tj.R[0]=1024; tj.C[0]=1024;
    tj.in[1]=Wsin; tj.out[1]=WbigT+1024*1024;  tj.R[1]=1024; tj.C[1]=256;
    tj.in[2]=Wd;   tj.out[2]=WbigT+1280*1024;  tj.R[2]=1024; tj.C[2]=256;
    tj.in[3]=Wsel; tj.out[3]=WbigT+1536*1024;  tj.R[3]=1024; tj.C[3]=256;
    tj.in[4]=Wg;   tj.out[4]=WbigT+(size_t)1792*1024; tj.R[4]=1024; tj.C[4]=1024;
    tj.in[5]=Wso;  tj.out[5]=WsoT;             tj.R[5]=256;  tj.C[5]=1024;
    tj.in[6]=Wout; tj.out[6]=WoutT;            tj.R[6]=1024; tj.C[6]=1024;
    transpose_all<<<dim3(32,32,7), dim3(32,8), 0, stream>>>(tj);

    ln_kernel  <<<M_, 256, 0, stream>>>(x, ln_g, ln_b, hB);
    conv_kernel<<<M_*128/256, 256, 0, stream>>>(hB, mixw, mixb, mixB);

    Epi e0 = {};
    e0.b0=bi; e0.b1=bsin; e0.b2=bd; e0.b3=bsel; e0.b4=bg;
    e0.u=uB; e0.g=gB; e0.xs=xs; e0.dc=dc; e0.sel=sel;
    gemm128<0><<<dim3(M_/128, 11), 512, 0, stream>>>(mixB, WbigT, 1024, e0);

    scan_p1<<<64, 256, 0, stream>>>(dc, xs, aggA, aggB);
    scan_p2<<<4,  256, 0, stream>>>(aggA, aggB, pre);
    scan_p3<<<64, 256, 0, stream>>>(dc, xs, sel, pre, ssB);

    Epi e1 = {};
    e1.b0=bso; e1.gbuf=gB; e1.ubuf=uB; e1.z=zB;
    gemm128<1><<<dim3(M_/128, 4), 512, 0, stream>>>(ssB, WsoT, 256, e1);

    Epi e2 = {};
    e2.b0=bout; e2.resid=x; e2.outp=out;
    gemm128<2><<<dim3(M_/128, 4), 512, 0, stream>>>(zB, WoutT, 1024, e2);
}

// Round 12
// 384.724 us; speedup vs baseline: 1.0595x; 1.0458x over previous
//
#include <hip/hip_runtime.h>
#include <hip/hip_bf16.h>
#include <math.h>

// ---------- types ----------
typedef __bf16 bf16_t;
typedef __bf16 bf16x8 __attribute__((ext_vector_type(8)));
typedef __bf16 bf16x4 __attribute__((ext_vector_type(4)));
typedef float  f32x4  __attribute__((ext_vector_type(4)));

#define B_ 4
#define S_ 4096
#define D_ 1024
#define N_ 256
#define M_ (B_*S_)   // 16384

// fast activations: v_exp_f32 + v_rcp_f32 (~1 ulp each, plenty for bf16 out)
__device__ __forceinline__ float fsig(float x){
    return __builtin_amdgcn_rcpf(1.0f + __expf(-x));
}
__device__ __forceinline__ float ftanh(float x){
    return 1.0f - 2.0f*__builtin_amdgcn_rcpf(1.0f + __expf(2.0f*x));
}

// async global->LDS, 16B per lane (dest = wave-uniform base + lane*16, linear)
__device__ __forceinline__ void gload_lds16(const void* g, void* l){
    __builtin_amdgcn_global_load_lds(
        (const __attribute__((address_space(1))) unsigned int*)g,
        (__attribute__((address_space(3))) unsigned int*)l, 16, 0, 0);
}

// ---------- all weight transposes in one launch ----------
// output layout is K-TILED: out[((k>>3)*ldn + noff + n)*8 + (k&7)] = W[k][n]
// so a GEMM B-fragment (16 consecutive n at one k-group of 8) is a contiguous
// 256B run -> coalesced global_load_dwordx4 directly from L2, no LDS staging.
struct TJobs {
    const float* in[7];
    bf16_t*      out[7];
    int R[7];     // K of this weight
    int C[7];     // N of this weight
    int ldn[7];   // total N of the k-tiled buffer it lives in
    int nf[7];    // column offset inside that buffer
};

__global__ void transpose_all(TJobs j){
    int z = blockIdx.z;
    int R = j.R[z], C = j.C[z];
    int c0 = blockIdx.x*32, r0 = blockIdx.y*32;
    if (c0 >= C || r0 >= R) return;
    __shared__ float tile[32][33];
    int tx = threadIdx.x, ty = threadIdx.y;       // x:0..31, y:0..7
    const float* in = j.in[z];
    bf16_t* out = j.out[z];
    int ldn = j.ldn[z], nf = j.nf[z];
    #pragma unroll
    for (int i=0;i<32;i+=8)
        tile[ty+i][tx] = in[(size_t)(r0+ty+i)*C + (c0+tx)];
    __syncthreads();
    #pragma unroll
    for (int i=0;i<32;i+=8){
        int r = r0+tx, c = c0+ty+i;
        out[((size_t)(r>>3)*ldn + nf + c)*8 + (r&7)] = (bf16_t)tile[tx][ty+i];
    }
}

// ---------- LayerNorm: x f32 [M][D] -> h bf16 ----------
__global__ void ln_kernel(const float* __restrict__ x, const float* __restrict__ gw,
                          const float* __restrict__ bw, bf16_t* __restrict__ h){
    int row = blockIdx.x;
    int t = threadIdx.x;                           // 256 threads, 4 elems each
    float4 v = ((const float4*)(x + (size_t)row*D_))[t];
    float s = v.x+v.y+v.z+v.w;
    float q = v.x*v.x+v.y*v.y+v.z*v.z+v.w*v.w;
    #pragma unroll
    for (int o=1;o<64;o<<=1){ s += __shfl_xor(s,o,64); q += __shfl_xor(q,o,64); }
    __shared__ float sw[4], sq[4];
    int wid = t>>6;
    if ((t&63)==0){ sw[wid]=s; sq[wid]=q; }
    __syncthreads();
    s = sw[0]+sw[1]+sw[2]+sw[3];
    q = sq[0]+sq[1]+sq[2]+sq[3];
    float mu = s*(1.0f/D_);
    float rs = rsqrtf(q*(1.0f/D_) - mu*mu + 1e-5f);
    float4 gv = ((const float4*)gw)[t];
    float4 bv = ((const float4*)bw)[t];
    bf16x4 o4;
    o4[0] = (bf16_t)((v.x-mu)*rs*gv.x + bv.x);
    o4[1] = (bf16_t)((v.y-mu)*rs*gv.y + bv.y);
    o4[2] = (bf16_t)((v.z-mu)*rs*gv.z + bv.z);
    o4[3] = (bf16_t)((v.w-mu)*rs*gv.w + bv.w);
    *(bf16x4*)(h + (size_t)row*D_ + t*4) = o4;
}

// ---------- depthwise conv1d k=3 pad=1 along S ----------
__global__ void conv_kernel(const bf16_t* __restrict__ h, const float* __restrict__ w,
                            const float* __restrict__ mb, bf16_t* __restrict__ mix){
    int idx = blockIdx.x*256 + threadIdx.x;
    int g8  = idx & 127;
    int row = idx >> 7;                            // b*S + s
    int s   = row & (S_-1);
    int d0  = g8*8;
    const bf16_t* hr = h + (size_t)row*D_ + d0;
    bf16x8 cur = *(const bf16x8*)hr;
    bf16x8 prv, nxt;
    #pragma unroll
    for (int i=0;i<8;i++){ prv[i]=(bf16_t)0.0f; nxt[i]=(bf16_t)0.0f; }
    if (s > 0)      prv = *(const bf16x8*)(hr - D_);
    if (s < S_-1)   nxt = *(const bf16x8*)(hr + D_);
    bf16x8 ov;
    #pragma unroll
    for (int i=0;i<8;i++){
        int d = d0+i;
        float o = (float)prv[i]*w[d*3] + (float)cur[i]*w[d*3+1] + (float)nxt[i]*w[d*3+2] + mb[d];
        ov[i] = (bf16_t)o;
    }
    *(bf16x8*)(mix + (size_t)row*D_ + d0) = ov;
}

// ---------- 128x256 MFMA GEMM: A via 3-buffer LDS, B direct from L2 ----------
// B (weights, L2-resident, k-tiled layout) loads straight to VGPRs (coalesced
// 256B/quad). A keeps the proven 3-buffer gload_lds rotation.
// PROLOGUE (r10 NaN fix): bF(0) loads strictly AFTER the prologue vmcnt(0)+barrier;
// mixing them with stage() builtins in one fence-free region lets the compiler
// reorder issue, breaking the vmcnt ledger -> aF(0) would read unwritten LDS.
//   prologue: stage(0,1,2); vmcnt(0); barrier;  bF(0); aF(0)
//   iter kt:  lgkmcnt(0); barrier;              // buf[kt%3] free
//             stage(kt+3)->buf[kt%3]; vmcnt(5)  // retires stage(kt+2) (no-op kt=0)
//             MFMAs; WAR-pinned reloads bF(kt+1) global, aF(kt+1) from LDS
struct Epi {
    const float *b0,*b1,*b2,*b3,*b4;
    bf16_t *u, *g, *z;
    bf16_t *xs, *dc, *sel;
    const bf16_t *gbuf, *ubuf;
    const float *resid;
    float *outp;
};

#define WAITV5()  asm volatile("s_waitcnt vmcnt(5)" ::: "memory")
#define WAITV0()  asm volatile("s_waitcnt vmcnt(0)" ::: "memory")
#define WAITLGK0() asm volatile("s_waitcnt lgkmcnt(0)" ::: "memory")
#define CFENCE()  asm volatile("" ::: "memory")
#define BARR()    __builtin_amdgcn_s_barrier()

template<int MODE>
__global__ __launch_bounds__(512,4)
void gemm128(const bf16_t* __restrict__ A, const bf16_t* __restrict__ Bt,
             int K, int NB, Epi e){
    __shared__ __align__(16) char lds[34816];   // A 3x8KB @0; epilogue scratch 33.3KB
    int t = threadIdx.x;
    int wave = t>>6, lane = t&63;
    int wm = (wave>>2)*64;                  // 2 wave-rows x 64
    int wn = (wave&3)*64;                   // 4 wave-cols x 64
    int lm = lane&15, quad = lane>>4;

    int m0 = blockIdx.x*128;
    int n0 = blockIdx.y*256;
    int NT = K>>5;                          // 32 or 8 (>=3)

    const bf16_t* gA = A + (size_t)(m0 + (t>>2))*K + (t&3)*8;
    // B k-tiled: element W[k][col] at Bt[((k>>3)*NB + col)*8 + (k&7)]
    // lane fragment base: kb=quad, col = n0+wn+lm (j adds 16 cols = 128 elems)
    const bf16_t* gBq = Bt + ((size_t)quad*NB + n0 + wn + lm)*8;
    const size_t ktStep = (size_t)32*NB;    // one K-tile (4 kb-groups) in elems

    auto stage = [&](int kt){
        char* da = lds + (kt%3)*8192 + t*16;
        gload_lds16(gA + kt*32, da);
    };

    int raBase = (wm+lm)*64 + quad*16;

    f32x4 acc[4][4];
    #pragma unroll
    for (int i=0;i<4;i++)
        #pragma unroll
        for (int j=0;j<4;j++)
            #pragma unroll
            for (int r=0;r<4;r++) acc[i][j][r]=0.0f;

    bf16x8 aF[4], bF[4];

    // ---- prologue: stage A(0,1,2); drain; THEN load bF(0) and aF(0) ----
    stage(0);
    stage(1);
    stage(2);
    WAITV0();                    // A(0..2) certified (own), deterministic order
    BARR();                      // ...certified by ALL waves
    CFENCE();
    #pragma unroll
    for (int j=0;j<4;j++) bF[j] = *(const bf16x8*)(gBq + j*128);
    {
        const char* pa = lds + raBase;      // buf0
        #pragma unroll
        for (int i=0;i<4;i++) aF[i] = *(const bf16x8*)(pa + i*1024);
    }

    for (int kt=0; kt<NT; ++kt){
        WAITLGK0();                      // our aF reads of tile kt complete
        BARR();                          // buf[kt%3] free for restaging
        CFENCE();
        if (kt+3 < NT){
            stage(kt+3);                 // into buf[kt%3]; overlaps MFMAs
            WAITV5();                    // kt=0: no-op; kt>=1: retires stage(kt+2)
        } else {
            WAITV0();                    // tail: drain
        }
        CFENCE();

        bool more = (kt+1 < NT);
        const char* pan = lds + ((kt+1)%3)*8192 + raBase;
        const bf16_t* gBn = gBq + (size_t)(kt+1)*ktStep;

        // j-outer MFMAs; reload bF[j] (global, L2) right after its last use
        #pragma unroll
        for (int j=0;j<4;j++){
            #pragma unroll
            for (int i=0;i<4;i++)
                acc[i][j] = __builtin_amdgcn_mfma_f32_16x16x32_bf16(aF[i], bF[j], acc[i][j], 0,0,0);
            if (more) bF[j] = *(const bf16x8*)(gBn + j*128);
        }
        if (more){
            #pragma unroll
            for (int i=0;i<4;i++) aF[i] = *(const bf16x8*)(pan + i*1024);
        }
    }
    __syncthreads();

    // ---- epilogue: retile through LDS for coalesced global I/O ----
    // acc layout: row = wm + i*16 + quad*4 + r, col = wn + j*16 + lm (128x256 tile)
    if (MODE==0 || MODE==1){
        const float* bp = e.b0; int cbase = 0; bf16_t* dst = 0; int width = D_;
        bool ut = true;
        if (MODE==0){
            ut = (n0 < 1280);
            if (n0 < 1024){ bp=e.b0; cbase=n0; dst=e.u; width=D_; }
            else if (n0 < 1792){
                int sub=(n0-1024)>>8;
                bp  = sub==0? e.b1 : sub==1? e.b2 : e.b3;
                dst = sub==0? e.xs : sub==1? e.dc : e.sel;
                cbase = 0; width = N_;
            } else { bp=e.b4; cbase=n0-1792; dst=e.g; width=D_; }
        } else {
            bp = e.b0; cbase = n0; width = D_;
        }
        bf16_t* Tb = (bf16_t*)lds;
        #pragma unroll
        for (int h=0; h<2; h++){                      // 64-row bands, stride 260
            if (h) __syncthreads();
            if (wm == h*64){
                #pragma unroll
                for (int ii=0;ii<4;ii++){
                    #pragma unroll
                    for (int j=0;j<4;j++){
                        float bv = bp[(MODE==0?cbase:n0) + wn + j*16 + lm];
                        #pragma unroll
                        for (int r=0;r<4;r++){
                            float v = acc[ii][j][r] + bv;
                            if (MODE==0) v = ut ? ftanh(v) : fsig(v);
                            Tb[(ii*16+quad*4+r)*260 + wn + j*16 + lm] = (bf16_t)v;
                        }
                    }
                }
            }
            __syncthreads();
            if (MODE==0){
                #pragma unroll
                for (int it=0; it<4; it++){
                    int idx = it*512 + t;
                    int row = idx>>5, c8 = idx&31;
                    bf16x8 v = *(const bf16x8*)&Tb[row*260 + c8*8];
                    *(bf16x8*)&dst[(size_t)(m0 + h*64 + row)*width + cbase + c8*8] = v;
                }
            } else {
                #pragma unroll
                for (int it=0; it<4; it++){
                    int idx = it*512 + t;
                    int row = idx>>5, c8 = idx&31;
                    bf16x8 y = *(const bf16x8*)&Tb[row*260 + c8*8];
                    size_t gi = (size_t)(m0 + h*64 + row)*D_ + n0 + c8*8;
                    bf16x8 gv = *(const bf16x8*)&e.gbuf[gi];
                    bf16x8 uv = *(const bf16x8*)&e.ubuf[gi];
                    bf16x8 o;
                    #pragma unroll
                    for (int q=0;q<8;q++){
                        float gf = (float)gv[q];
                        o[q] = (bf16_t)(gf*(float)y[q] + (1.0f-gf)*(float)uv[q]);
                    }
                    *(bf16x8*)&e.z[gi] = o;
                }
            }
        }
    } else {
        float* T = (float*)lds;
        #pragma unroll
        for (int pZ=0; pZ<4; pZ++){                   // 32-row bands, stride 260
            if (pZ) __syncthreads();
            if (wm == (pZ>>1)*64){
                int ib = (pZ&1)*2;
                #pragma unroll
                for (int ii=0;ii<2;ii++){
                    #pragma unroll
                    for (int j=0;j<4;j++)
                        #pragma unroll
                        for (int r=0;r<4;r++)
                            T[(ii*16+quad*4+r)*260 + wn + j*16 + lm] = acc[ib+ii][j][r];
                }
            }
            __syncthreads();
            #pragma unroll
            for (int it=0; it<4; it++){
                int idx = it*512 + t;
                int row = idx>>6, c4 = idx&63;
                f32x4 v = *(const f32x4*)&T[row*260 + c4*4];
                size_t gi = (size_t)(m0 + pZ*32 + row)*D_ + n0 + c4*4;
                float4 res = *(const float4*)&e.resid[gi];
                float4 bb  = *(const float4*)&e.b0[n0 + c4*4];
                float4 o;
                o.x = v[0]+res.x+bb.x; o.y = v[1]+res.y+bb.y;
                o.z = v[2]+res.z+bb.z; o.w = v[3]+res.w+bb.w;
                *(float4*)&e.outp[gi] = o;
            }
        }
    }
}

// ---------- chunked affine scan: state = d*state + (1-d)*x (bf16 in, bf16 out) ----------
// one wave per (b,chunk); each lane owns 4 contiguous channels (bf16x4 = 8B/lane)
__global__ void scan_p1(const bf16_t* __restrict__ dc, const bf16_t* __restrict__ xs,
                        float* __restrict__ aggA, float* __restrict__ aggB){
    int wg4 = blockIdx.x*4 + (threadIdx.x>>6);     // b*64 + chunk
    int b = wg4>>6, ch = wg4&63;
    int l4 = (threadIdx.x&63)*4;
    size_t base = ((size_t)b*S_ + ch*64)*N_ + l4;
    float A0=1.f,A1=1.f,A2=1.f,A3=1.f, B0=0.f,B1=0.f,B2=0.f,B3=0.f;
    for (int t=0;t<64;t++){
        bf16x4 d4 = *(const bf16x4*)(dc + base + (size_t)t*N_);
        bf16x4 x4 = *(const bf16x4*)(xs + base + (size_t)t*N_);
        float d;
        d=(float)d4[0]; A0*=d; B0=d*B0+(1.f-d)*(float)x4[0];
        d=(float)d4[1]; A1*=d; B1=d*B1+(1.f-d)*(float)x4[1];
        d=(float)d4[2]; A2*=d; B2=d*B2+(1.f-d)*(float)x4[2];
        d=(float)d4[3]; A3*=d; B3=d*B3+(1.f-d)*(float)x4[3];
    }
    size_t o = (size_t)wg4*N_ + l4;
    float4 av; av.x=A0; av.y=A1; av.z=A2; av.w=A3;
    float4 bv; bv.x=B0; bv.y=B1; bv.z=B2; bv.w=B3;
    *(float4*)(aggA+o) = av;
    *(float4*)(aggB+o) = bv;
}

// wave-parallel affine scan across 64 chunks (Kogge-Stone compose), one wave/chain
__global__ void scan_p2(const float* __restrict__ aggA, const float* __restrict__ aggB,
                        float* __restrict__ pre){
    int chain = blockIdx.x*4 + (threadIdx.x>>6);   // b*256 + n, 1024 chains
    int lane  = threadIdx.x & 63;                  // chunk index
    int b = chain>>8, n = chain&255;
    size_t i = ((size_t)b*64 + lane)*N_ + n;
    float A = aggA[i], Bv = aggB[i];
    #pragma unroll
    for (int off=1; off<64; off<<=1){
        float Ap = __shfl_up(A, off, 64);
        float Bp = __shfl_up(Bv, off, 64);
        if (lane >= off){ Bv = A*Bp + Bv; A = A*Ap; }
    }
    float preB = __shfl_up(Bv, 1, 64);             // exclusive: state before chunk
    if (lane == 0) preB = 0.0f;
    pre[i] = preB;
}

__global__ void scan_p3(const bf16_t* __restrict__ dc, const bf16_t* __restrict__ xs,
                        const bf16_t* __restrict__ sel, const float* __restrict__ pre,
                        bf16_t* __restrict__ ss){
    int wg4 = blockIdx.x*4 + (threadIdx.x>>6);
    int b = wg4>>6, ch = wg4&63;
    int l4 = (threadIdx.x&63)*4;
    size_t base = ((size_t)b*S_ + ch*64)*N_ + l4;
    size_t o = (size_t)wg4*N_ + l4;
    float4 pv = *(const float4*)(pre+o);
    float s0=pv.x, s1=pv.y, s2=pv.z, s3=pv.w;
    for (int t=0;t<64;t++){
        size_t i = base + (size_t)t*N_;
        bf16x4 d4 = *(const bf16x4*)(dc+i);
        bf16x4 x4 = *(const bf16x4*)(xs+i);
        bf16x4 e4 = *(const bf16x4*)(sel+i);
        float d;
        d=(float)d4[0]; s0=d*s0+(1.f-d)*(float)x4[0];
        d=(float)d4[1]; s1=d*s1+(1.f-d)*(float)x4[1];
        d=(float)d4[2]; s2=d*s2+(1.f-d)*(float)x4[2];
        d=(float)d4[3]; s3=d*s3+(1.f-d)*(float)x4[3];
        bf16x4 o4;
        o4[0]=(bf16_t)((float)e4[0]*s0);
        o4[1]=(bf16_t)((float)e4[1]*s1);
        o4[2]=(bf16_t)((float)e4[2]*s2);
        o4[3]=(bf16_t)((float)e4[3]*s3);
        *(bf16x4*)(ss+i) = o4;
    }
}

// ---------- launch ----------
extern "C" void kernel_launch(void* const* d_in, const int* in_sizes, int n_in,
                              void* d_out, int out_size, void* d_ws, size_t ws_size,
                              hipStream_t stream){
    const float* x    = (const float*)d_in[0];
    const float* ln_g = (const float*)d_in[1];
    const float* ln_b = (const float*)d_in[2];
    const float* mixw = (const float*)d_in[3];
    const float* mixb = (const float*)d_in[4];
    const float* Wi   = (const float*)d_in[5];
    const float* bi   = (const float*)d_in[6];
    const float* Wsin = (const float*)d_in[7];
    const float* bsin = (const float*)d_in[8];
    const float* Wd   = (const float*)d_in[9];
    const float* bd   = (const float*)d_in[10];
    const float* Wsel = (const float*)d_in[11];
    const float* bsel = (const float*)d_in[12];
    const float* Wso  = (const float*)d_in[13];
    const float* bso  = (const float*)d_in[14];
    const float* Wg   = (const float*)d_in[15];
    const float* bg   = (const float*)d_in[16];
    const float* Wout = (const float*)d_in[17];
    const float* bout = (const float*)d_in[18];
    float* out = (float*)d_out;

    char* p = (char*)d_ws;
    auto alloc = [&](size_t bytes)->char*{ char* r=p; p += (bytes+255)&~(size_t)255; return r; };
    bf16_t* hB    = (bf16_t*)alloc((size_t)M_*D_*2);
    bf16_t* mixB  = (bf16_t*)alloc((size_t)M_*D_*2);
    bf16_t* uB    = (bf16_t*)alloc((size_t)M_*D_*2);
    bf16_t* gB    = (bf16_t*)alloc((size_t)M_*D_*2);
    bf16_t* ssB   = (bf16_t*)alloc((size_t)M_*N_*2);
    bf16_t* xs    = (bf16_t*)alloc((size_t)M_*N_*2);
    bf16_t* dc    = (bf16_t*)alloc((size_t)M_*N_*2);
    bf16_t* sel   = (bf16_t*)alloc((size_t)M_*N_*2);
    bf16_t* WbigT = (bf16_t*)alloc((size_t)2816*1024*2);  // k-tiled [128][2816][8]
    bf16_t* WsoT  = (bf16_t*)alloc(1024*256*2);           // k-tiled [32][1024][8]
    bf16_t* WoutT = (bf16_t*)alloc(1024*1024*2);          // k-tiled [128][1024][8]
    float*  aggA  = (float*)alloc((size_t)4*64*256*4);
    float*  aggB  = (float*)alloc((size_t)4*64*256*4);
    float*  pre   = (float*)alloc((size_t)4*64*256*4);
    bf16_t* zB = mixB;

    TJobs tj;
    tj.in[0]=Wi;   tj.out[0]=WbigT; tj.R[0]=1024; tj.C[0]=1024; tj.ldn[0]=2816; tj.nf[0]=0;
    tj.in[1]=Wsin; tj.out[1]=WbigT; tj.R[1]=1024; tj.C[1]=256;  tj.ldn[1]=2816; tj.nf[1]=1024;
    tj.in[2]=Wd;   tj.out[2]=WbigT; tj.R[2]=1024; tj.C[2]=256;  tj.ldn[2]=2816; tj.nf[2]=1280;
    tj.in[3]=Wsel; tj.out[3]=WbigT; tj.R[3]=1024; tj.C[3]=256;  tj.ldn[3]=2816; tj.nf[3]=1536;
    tj.in[4]=Wg;   tj.out[4]=WbigT; tj.R[4]=1024; tj.C[4]=1024; tj.ldn[4]=2816; tj.nf[4]=1792;
    tj.in[5]=Wso;  tj.out[5]=WsoT;  tj.R[5]=256;  tj.C[5]=1024; tj.ldn[5]=1024; tj.nf[5]=0;
    tj.in[6]=Wout; tj.out[6]=WoutT; tj.R[6]=1024; tj.C[6]=1024; tj.ldn[6]=1024; tj.nf[6]=0;
    transpose_all<<<dim3(32,32,7), dim3(32,8), 0, stream>>>(tj);

    ln_kernel  <<<M_, 256, 0, stream>>>(x, ln_g, ln_b, hB);
    conv_kernel<<<M_*128/256, 256, 0, stream>>>(hB, mixw, mixb, mixB);

    Epi e0 = {};
    e0.b0=bi; e0.b1=bsin; e0.b2=bd; e0.b3=bsel; e0.b4=bg;
    e0.u=uB; e0.g=gB; e0.xs=xs; e0.dc=dc; e0.sel=sel;
    gemm128<0><<<dim3(M_/128, 11), 512, 0, stream>>>(mixB, WbigT, 1024, 2816, e0);

    scan_p1<<<64,  256, 0, stream>>>(dc, xs, aggA, aggB);
    scan_p2<<<256, 256, 0, stream>>>(aggA, aggB, pre);
    scan_p3<<<64,  256, 0, stream>>>(dc, xs, sel, pre, ssB);

    Epi e1 = {};
    e1.b0=bso; e1.gbuf=gB; e1.ubuf=uB; e1.z=zB;
    gemm128<1><<<dim3(M_/128, 4), 512, 0, stream>>>(ssB, WsoT, 256, 1024, e1);

    Epi e2 = {};
    e2.b0=bout; e2.resid=x; e2.outp=out;
    gemm128<2><<<dim3(M_/128, 4), 512, 0, stream>>>(zB, WoutT, 1024, 1024, e2);
}